// Round 15
// baseline (158.555 us; speedup 1.0000x reference)
//
#include <hip/hip_runtime.h>
#include <hip/hip_bf16.h>

#define NN 100000
#define NE 800000
#define EBLK 391        // ceil(NE/2048)
#define NBUK 196        // ceil(NN/512), bucket = dst >> 9
#define BSTRIDE 6144    // fixed per-bucket capacity (expected 4082 +/- 64)

typedef __attribute__((ext_vector_type(8))) short bf16x8;
typedef __attribute__((ext_vector_type(4))) float f32x4;

__device__ __forceinline__ unsigned short f2b(float f) {
  unsigned int x = __float_as_uint(f);
  return (unsigned short)((x + 0x7fffu + ((x >> 16) & 1u)) >> 16);
}
__device__ __forceinline__ float b2f(short us) {
  return __uint_as_float(((unsigned int)(unsigned short)us) << 16);
}
__device__ __forceinline__ void acc8(float* acc, bf16x8 v) {
#pragma unroll
  for (int i = 0; i < 8; ++i) acc[i] += b2f(v[i]);
}

// ---------------- CSR build (2 kernels) + weight conversion merged ----------------
static __global__ __launch_bounds__(256) void k_scwc(const int* __restrict__ src, const int* __restrict__ dst,
                                                     int* __restrict__ gcur, int* __restrict__ ebuf,
    const float* __restrict__ W1, const float* __restrict__ W2, const float* __restrict__ W3,
    const float* __restrict__ Wf1, const float* __restrict__ Wf2, const float* __restrict__ Wf3,
    short* __restrict__ W1t, short* __restrict__ W2t, short* __restrict__ W3t,
    short* __restrict__ Wf1t, short* __restrict__ Wf2t, short* __restrict__ Wf3t) {
  int tid = threadIdx.x, blk = blockIdx.x;
  if (blk >= EBLK) {
    int b = blk - EBLK;
    if (b < 5) {
      const float* W = (b == 0) ? W1 : (b == 1) ? W2 : (b == 2) ? W3 : (b == 3) ? Wf1 : Wf2;
      short* Wt = (b == 0) ? W1t : (b == 1) ? W2t : (b == 2) ? W3t : (b == 3) ? Wf1t : Wf2t;
#pragma unroll
      for (int i = 0; i < 16; ++i) {
        int idx = tid + 256 * i;       // = k*64 + n
        int k = idx >> 6, nn = idx & 63;
        Wt[nn * 64 + k] = (short)f2b(W[idx]);
      }
    } else {
#pragma unroll
      for (int i = 0; i < 4; ++i) {
        int idx = tid + 256 * i;       // = k*16 + n
        int k = idx >> 4, nn = idx & 15;
        Wf3t[nn * 64 + k] = (short)f2b(Wf3[idx]);
      }
    }
    return;
  }
  __shared__ int hist[256];
  __shared__ int lstart[256];
  __shared__ int gbase[256];
  __shared__ int cur[NBUK];
  __shared__ int wsum[4];
  __shared__ int2 sbuf[2048];
  int lane = tid & 63, wv = tid >> 6;
  hist[tid] = 0;
  __syncthreads();
  int base = blk * 2048;
  int dd[8], ss[8];
#pragma unroll
  for (int i = 0; i < 8; ++i) {
    int e = base + tid + 256 * i;
    if (e < NE) {
      dd[i] = dst[e]; ss[i] = src[e];
      atomicAdd(&hist[dd[i] >> 9], 1);
    } else dd[i] = -1;
  }
  __syncthreads();
  int v = hist[tid];
  // wave-level inclusive scan of v over 256 threads (1 barrier total)
  int s = v;
#pragma unroll
  for (int off = 1; off < 64; off <<= 1) {
    int t = __shfl_up(s, off);
    if (lane >= off) s += t;
  }
  if (lane == 63) wsum[wv] = s;
  __syncthreads();
  int wpre = 0;
#pragma unroll
  for (int i = 0; i < 4; ++i) wpre += (i < wv) ? wsum[i] : 0;
  int excl = s + wpre - v;
  lstart[tid] = excl;
  if (tid < NBUK) {
    cur[tid] = 0;
    gbase[tid] = (v > 0) ? atomicAdd(&gcur[tid], v) : 0;
  }
  __syncthreads();
#pragma unroll
  for (int i = 0; i < 8; ++i) {
    if (dd[i] >= 0) {
      int b = dd[i] >> 9;
      int p = atomicAdd(&cur[b], 1);
      sbuf[lstart[b] + p] = make_int2((ss[i] << 9) | (dd[i] & 511), b);
    }
  }
  __syncthreads();
  int m = NE - base; if (m > 2048) m = 2048;
#pragma unroll
  for (int i = 0; i < 8; ++i) {
    int j = tid + 256 * i;
    if (j < m) {
      int2 e = sbuf[j];
      int b = e.y;
      int gpos = b * BSTRIDE + gbase[b] + (j - lstart[b]);
      ebuf[gpos] = e.x;
    }
  }
}

static __global__ __launch_bounds__(256) void k_bucket(const int* __restrict__ ebuf, const int* __restrict__ gcur,
                                                       int4* __restrict__ rc4, float* __restrict__ dis,
                                                       int* __restrict__ col_idx) {
  __shared__ int cnt[512];
  __shared__ int lrs[512];
  __shared__ int wsum[4];
  int b = blockIdx.x, tid = threadIdx.x;
  int lane = tid & 63, wv = tid >> 6;
  int base_n = b << 9;
  int ebeg = b * BSTRIDE;
  int m = gcur[b];
  cnt[tid] = 0; cnt[tid + 256] = 0;
  __syncthreads();
  for (int j = tid; j < m; j += 256) atomicAdd(&cnt[ebuf[ebeg + j] & 511], 1);
  __syncthreads();
  int v0 = cnt[2 * tid], v1 = cnt[2 * tid + 1];
  int sv = v0 + v1;
  int s = sv;
#pragma unroll
  for (int off = 1; off < 64; off <<= 1) {
    int t = __shfl_up(s, off);
    if (lane >= off) s += t;
  }
  if (lane == 63) wsum[wv] = s;
  __syncthreads();
  int wpre = 0;
#pragma unroll
  for (int i = 0; i < 4; ++i) wpre += (i < wv) ? wsum[i] : 0;
  int excl = s + wpre - sv;
  lrs[2 * tid] = excl;
  lrs[2 * tid + 1] = excl + v0;
  __syncthreads();
  for (int i = tid; i < 512; i += 256) {
    int n = base_n + i;
    if (n < NN) {
      int c = cnt[i];
      float d = 1.0f / sqrtf((float)c + 1.0f);
      rc4[n] = make_int4(ebeg + lrs[i], c, __float_as_int(d), 0);
      dis[n] = d;
    }
  }
  for (int i = tid; i < 512; i += 256) cnt[i] = lrs[i];
  __syncthreads();
  for (int j = tid; j < m; j += 256) {
    int e = ebuf[ebeg + j];
    int p = atomicAdd(&cnt[e & 511], 1);
    col_idx[ebeg + p] = e >> 9;
  }
}

__device__ __forceinline__ bf16x8 load_a_frag_f32(const float* __restrict__ p, bool valid) {
  float4 f0 = valid ? *(const float4*)p : make_float4(0.f, 0.f, 0.f, 0.f);
  float4 f1 = valid ? *(const float4*)(p + 4) : make_float4(0.f, 0.f, 0.f, 0.f);
  bf16x8 a;
  a[0] = (short)f2b(f0.x); a[1] = (short)f2b(f0.y); a[2] = (short)f2b(f0.z); a[3] = (short)f2b(f0.w);
  a[4] = (short)f2b(f1.x); a[5] = (short)f2b(f1.y); a[6] = (short)f2b(f1.z); a[7] = (short)f2b(f1.w);
  return a;
}

// shared MFMA body: writes ht (bf16, dis-scaled)
__device__ __forceinline__ void mm_body(bf16x8 a0, bf16x8 a1, const short* __restrict__ Wt,
                                        const float* __restrict__ dis, short* __restrict__ out,
                                        int row0, int rlane, int g, int n) {
  f32x4 acc[4];
#pragma unroll
  for (int t = 0; t < 4; ++t) acc[t] = (f32x4){0.f, 0.f, 0.f, 0.f};
#pragma unroll
  for (int t = 0; t < 4; ++t) {
    bf16x8 b0 = *(const bf16x8*)(Wt + (rlane + 16 * t) * 64 + g * 8);
    bf16x8 b1 = *(const bf16x8*)(Wt + (rlane + 16 * t) * 64 + g * 8 + 32);
    acc[t] = __builtin_amdgcn_mfma_f32_16x16x32_bf16(a0, b0, acc[t], 0, 0, 0);
    acc[t] = __builtin_amdgcn_mfma_f32_16x16x32_bf16(a1, b1, acc[t], 0, 0, 0);
  }
#pragma unroll
  for (int r = 0; r < 4; ++r) {
    int gr = row0 + g * 4 + r;
    if (gr < n) {
      float s = dis[gr];
#pragma unroll
      for (int t = 0; t < 4; ++t)
        out[(size_t)gr * 64 + rlane + 16 * t] = (short)f2b(acc[t][r] * s);
    }
  }
}

// layer-1: f32 input, ht1 = (x @ W1) * dis
static __global__ __launch_bounds__(256) void k_mm1(const float* __restrict__ in, const short* __restrict__ Wt,
                                                    const float* __restrict__ dis, short* __restrict__ out, int n) {
  int tid = threadIdx.x;
  int lane = tid & 63, w = tid >> 6;
  int row0 = blockIdx.x * 64 + w * 16;
  int rlane = lane & 15, g = lane >> 4;
  int arow = row0 + rlane;
  bool av = arow < n;
  const float* ap = in + (size_t)arow * 64 + g * 8;
  bf16x8 a0 = load_a_frag_f32(ap, av);
  bf16x8 a1 = load_a_frag_f32(ap + 32, av);
  mm_body(a0, a1, Wt, dis, out, row0, rlane, g, n);
}

// agg: ONE node per 8-lane group, 8 nodes/wave. Per 8-edge chunk: broadcast all
// 8 indices, issue ALL 8 row-loads (invalid -> row 0, cache-hot), wait once,
// accumulate guarded. Writes rows [wrow0, wrow0+8) of Hs.
__device__ __forceinline__ void agg8_to_lds(const short* __restrict__ ht, const int4* __restrict__ rc4,
                                            const int* __restrict__ col_idx,
                                            const float* __restrict__ bias, short (*Hs)[72],
                                            int nodebase, int wrow0, int lane, int n) {
  int g = lane >> 3, f = lane & 7;
  float4 b0v = *(const float4*)&bias[f * 8];
  float4 b1v = *(const float4*)&bias[f * 8 + 4];
  float bb[8] = {b0v.x, b0v.y, b0v.z, b0v.w, b1v.x, b1v.y, b1v.z, b1v.w};
  int node = nodebase + g;
  bool nv = node < n;
  int4 rcv = nv ? rc4[node] : make_int4(0, 0, 0, 0);
  int beg = rcv.x, cnt = rcv.y;
  float ds = nv ? __int_as_float(rcv.z) : 0.f;
  float acc[8] = {0.f, 0.f, 0.f, 0.f, 0.f, 0.f, 0.f, 0.f};
  if (nv) acc8(acc, *(const bf16x8*)(ht + (size_t)node * 64 + f * 8));   // self-loop
  for (int base = 0; base < cnt; base += 8) {
    int idx = (base + f < cnt) ? col_idx[beg + base + f] : 0;
    int s[8];
#pragma unroll
    for (int e = 0; e < 8; ++e) s[e] = __shfl(idx, g * 8 + e);
    bf16x8 r[8];
#pragma unroll
    for (int e = 0; e < 8; ++e) r[e] = *(const bf16x8*)(ht + (size_t)s[e] * 64 + f * 8);
    int mm = cnt - base; if (mm > 8) mm = 8;
#pragma unroll
    for (int e = 0; e < 8; ++e) { if (e < mm) acc8(acc, r[e]); }
  }
  bf16x8 o;
#pragma unroll
  for (int i = 0; i < 8; ++i)
    o[i] = (short)f2b(fmaxf(fmaf(ds, acc[i], bb[i]), 0.f));
  *(bf16x8*)&Hs[wrow0 + g][f * 8] = o;
}

// fused: agg -> matmul. 64-thread blocks, 8 nodes each (grid 12500 independent
// waves, ZERO barriers). MFMA tile rows 8..15 are garbage (D rows independent,
// never stored); only g<2 stores.
static __global__ __launch_bounds__(64) void k_aggmm(const short* __restrict__ ht, const int4* __restrict__ rc4,
                                                     const int* __restrict__ col_idx, const float* __restrict__ dis,
                                                     const float* __restrict__ bias, const short* __restrict__ Wt,
                                                     short* __restrict__ out, int n) {
  __shared__ __align__(16) short Hs[16][72];
  int lane = threadIdx.x;
  int row0 = blockIdx.x * 8;
  agg8_to_lds(ht, rc4, col_idx, bias, Hs, row0, 0, lane, n);
  int rlane = lane & 15, g = lane >> 4;
  bf16x8 a0 = *(const bf16x8*)&Hs[rlane][g * 8];
  bf16x8 a1 = *(const bf16x8*)&Hs[rlane][g * 8 + 32];
  f32x4 acc[4];
#pragma unroll
  for (int t = 0; t < 4; ++t) acc[t] = (f32x4){0.f, 0.f, 0.f, 0.f};
#pragma unroll
  for (int t = 0; t < 4; ++t) {
    bf16x8 b0 = *(const bf16x8*)(Wt + (rlane + 16 * t) * 64 + g * 8);
    bf16x8 b1 = *(const bf16x8*)(Wt + (rlane + 16 * t) * 64 + g * 8 + 32);
    acc[t] = __builtin_amdgcn_mfma_f32_16x16x32_bf16(a0, b0, acc[t], 0, 0, 0);
    acc[t] = __builtin_amdgcn_mfma_f32_16x16x32_bf16(a1, b1, acc[t], 0, 0, 0);
  }
  if (g < 2) {
#pragma unroll
    for (int r = 0; r < 4; ++r) {
      int gr = row0 + g * 4 + r;
      if (gr < n) {
        float s = dis[gr];
#pragma unroll
        for (int t = 0; t < 4; ++t)
          out[(size_t)gr * 64 + rlane + 16 * t] = (short)f2b(acc[t][r] * s);
      }
    }
  }
}

// fused: agg -> MLP head -> log_softmax. 64-thread blocks, 8 nodes, no barriers.
static __global__ __launch_bounds__(64) void k_aggdense(const short* __restrict__ ht, const int4* __restrict__ rc4,
    const int* __restrict__ col_idx, const float* __restrict__ bias,
    const short* __restrict__ W1t, const float* __restrict__ bf1,
    const short* __restrict__ W2t, const float* __restrict__ bf2,
    const short* __restrict__ W3t, const float* __restrict__ bf3,
    float* __restrict__ out, int n) {
  __shared__ __align__(16) short Hs[16][72];
  __shared__ __align__(16) short H2[16][72];
  int lane = threadIdx.x;
  int row0 = blockIdx.x * 8;
  agg8_to_lds(ht, rc4, col_idx, bias, Hs, row0, 0, lane, n);
  int rlane = lane & 15, g = lane >> 4;
  // L1
  {
    bf16x8 a0 = *(const bf16x8*)&Hs[rlane][g * 8];
    bf16x8 a1 = *(const bf16x8*)&Hs[rlane][g * 8 + 32];
#pragma unroll
    for (int t = 0; t < 4; ++t) {
      bf16x8 b0 = *(const bf16x8*)(W1t + (rlane + 16 * t) * 64 + g * 8);
      bf16x8 b1 = *(const bf16x8*)(W1t + (rlane + 16 * t) * 64 + g * 8 + 32);
      f32x4 acc = (f32x4){0.f, 0.f, 0.f, 0.f};
      acc = __builtin_amdgcn_mfma_f32_16x16x32_bf16(a0, b0, acc, 0, 0, 0);
      acc = __builtin_amdgcn_mfma_f32_16x16x32_bf16(a1, b1, acc, 0, 0, 0);
      if (g < 2) {
        float bb = bf1[16 * t + rlane];
#pragma unroll
        for (int r = 0; r < 4; ++r)
          H2[g * 4 + r][16 * t + rlane] = (short)f2b(fmaxf(acc[r] + bb, 0.f));
      }
    }
  }
  // L2
  {
    bf16x8 c0 = *(const bf16x8*)&H2[rlane][g * 8];
    bf16x8 c1 = *(const bf16x8*)&H2[rlane][g * 8 + 32];
#pragma unroll
    for (int t = 0; t < 4; ++t) {
      bf16x8 b0 = *(const bf16x8*)(W2t + (rlane + 16 * t) * 64 + g * 8);
      bf16x8 b1 = *(const bf16x8*)(W2t + (rlane + 16 * t) * 64 + g * 8 + 32);
      f32x4 acc = (f32x4){0.f, 0.f, 0.f, 0.f};
      acc = __builtin_amdgcn_mfma_f32_16x16x32_bf16(c0, b0, acc, 0, 0, 0);
      acc = __builtin_amdgcn_mfma_f32_16x16x32_bf16(c1, b1, acc, 0, 0, 0);
      if (g < 2) {
        float bb = bf2[16 * t + rlane];
#pragma unroll
        for (int r = 0; r < 4; ++r)
          Hs[g * 4 + r][16 * t + rlane] = (short)f2b(fmaxf(acc[r] + bb, 0.f));
      }
    }
  }
  // L3 + log_softmax
  {
    bf16x8 d0 = *(const bf16x8*)&Hs[rlane][g * 8];
    bf16x8 d1 = *(const bf16x8*)&Hs[rlane][g * 8 + 32];
    bf16x8 e0 = *(const bf16x8*)(W3t + rlane * 64 + g * 8);
    bf16x8 e1 = *(const bf16x8*)(W3t + rlane * 64 + g * 8 + 32);
    f32x4 z = (f32x4){0.f, 0.f, 0.f, 0.f};
    z = __builtin_amdgcn_mfma_f32_16x16x32_bf16(d0, e0, z, 0, 0, 0);
    z = __builtin_amdgcn_mfma_f32_16x16x32_bf16(d1, e1, z, 0, 0, 0);
    float bsc = bf3[rlane];
#pragma unroll
    for (int r = 0; r < 4; ++r) {
      float zz = z[r] + bsc;
      float mx = zz;
      mx = fmaxf(mx, __shfl_xor(mx, 1));
      mx = fmaxf(mx, __shfl_xor(mx, 2));
      mx = fmaxf(mx, __shfl_xor(mx, 4));
      mx = fmaxf(mx, __shfl_xor(mx, 8));
      float ex = __expf(zz - mx);
      ex += __shfl_xor(ex, 1);
      ex += __shfl_xor(ex, 2);
      ex += __shfl_xor(ex, 4);
      ex += __shfl_xor(ex, 8);
      float lse = mx + __logf(ex);
      int gr = row0 + g * 4 + r;
      if (g < 2 && gr < n) out[(size_t)gr * 16 + rlane] = zz - lse;
    }
  }
}

extern "C" void kernel_launch(void* const* d_in, const int* in_sizes, int n_in,
                              void* d_out, int out_size, void* d_ws, size_t ws_size,
                              hipStream_t stream) {
  (void)in_sizes; (void)n_in; (void)out_size; (void)ws_size;
  const float* x   = (const float*)d_in[0];
  const int*   ei  = (const int*)d_in[1];
  const float* W1  = (const float*)d_in[2];
  const float* b1  = (const float*)d_in[3];
  const float* W2  = (const float*)d_in[4];
  const float* b2  = (const float*)d_in[5];
  const float* W3  = (const float*)d_in[6];
  const float* b3  = (const float*)d_in[7];
  const float* Wf1 = (const float*)d_in[8];
  const float* bf1 = (const float*)d_in[9];
  const float* Wf2 = (const float*)d_in[10];
  const float* bf2 = (const float*)d_in[11];
  const float* Wf3 = (const float*)d_in[12];
  const float* bf3 = (const float*)d_in[13];
  float* outp = (float*)d_out;
  const int* srcp = ei;
  const int* dstp = ei + NE;

  char* ws = (char*)d_ws;
  size_t off = 0;
  auto alloc = [&](size_t bytes) { void* p = ws + off; off = (off + bytes + 255) & ~(size_t)255; return p; };
  int4*  rc4    = (int4*)alloc((size_t)NN * 16);
  float* dis    = (float*)alloc((size_t)NN * 4);
  int*   gcur   = (int*)alloc(256 * 4);
  int*   colidx = (int*)alloc((size_t)NBUK * BSTRIDE * 4);
  short* W1t    = (short*)alloc(4096 * 2);
  short* W2t    = (short*)alloc(4096 * 2);
  short* W3t    = (short*)alloc(4096 * 2);
  short* Wf1t   = (short*)alloc(4096 * 2);
  short* Wf2t   = (short*)alloc(4096 * 2);
  short* Wf3t   = (short*)alloc(1024 * 2);
  short* bufA   = (short*)alloc((size_t)NN * 64 * 2);
  short* bufB   = (short*)alloc((size_t)NN * 64 * 2);
  int*   ebuf   = (int*)alloc((size_t)NBUK * BSTRIDE * 4);

  int gMM = (NN + 63) / 64;      // 1563 (256-thread blocks)
  int gAG = (NN + 7) / 8;        // 12500 (64-thread single-wave blocks)

  hipMemsetAsync(gcur, 0, 256 * 4, stream);
  k_scwc<<<EBLK + 6, 256, 0, stream>>>(srcp, dstp, gcur, ebuf,
                                       W1, W2, W3, Wf1, Wf2, Wf3,
                                       W1t, W2t, W3t, Wf1t, Wf2t, Wf3t);
  k_bucket<<<NBUK, 256, 0, stream>>>(ebuf, gcur, rc4, dis, colidx);

  // ht1 = (x @ W1) * dis
  k_mm1<<<gMM, 256, 0, stream>>>(x, W1t, dis, bufB, NN);
  // h1 = relu(dis*(agg ht1) + b1); ht2 = (h1 @ W2) * dis
  k_aggmm<<<gAG, 64, 0, stream>>>(bufB, rc4, colidx, dis, b1, W2t, bufA, NN);
  // h2 = relu(dis*(agg ht2) + b2); ht3 = (h2 @ W3) * dis
  k_aggmm<<<gAG, 64, 0, stream>>>(bufA, rc4, colidx, dis, b2, W3t, bufB, NN);
  // h3 = relu(dis*(agg ht3) + b3); out = log_softmax(MLP(h3))
  k_aggdense<<<gAG, 64, 0, stream>>>(bufB, rc4, colidx, b3,
                                     Wf1t, bf1, Wf2t, bf2, Wf3t, bf3, outp, NN);
}

// Round 16
// 134.823 us; speedup vs baseline: 1.1760x; 1.1760x over previous
//
#include <hip/hip_runtime.h>
#include <hip/hip_bf16.h>

#define NN 100000
#define NE 800000
#define EBLK 391        // ceil(NE/2048)
#define NBUK 196        // ceil(NN/512), bucket = dst >> 9
#define BSTRIDE 6144    // fixed per-bucket capacity (expected 4082 +/- 64)

typedef __attribute__((ext_vector_type(8))) short bf16x8;
typedef __attribute__((ext_vector_type(4))) float f32x4;

__device__ __forceinline__ unsigned short f2b(float f) {
  unsigned int x = __float_as_uint(f);
  return (unsigned short)((x + 0x7fffu + ((x >> 16) & 1u)) >> 16);
}
__device__ __forceinline__ float b2f(short us) {
  return __uint_as_float(((unsigned int)(unsigned short)us) << 16);
}
__device__ __forceinline__ void acc8(float* acc, bf16x8 v) {
#pragma unroll
  for (int i = 0; i < 8; ++i) acc[i] += b2f(v[i]);
}

// ---------------- CSR build (2 kernels) + weight conversion merged ----------------
static __global__ __launch_bounds__(256) void k_scwc(const int* __restrict__ src, const int* __restrict__ dst,
                                                     int* __restrict__ gcur, int* __restrict__ ebuf,
    const float* __restrict__ W1, const float* __restrict__ W2, const float* __restrict__ W3,
    const float* __restrict__ Wf1, const float* __restrict__ Wf2, const float* __restrict__ Wf3,
    short* __restrict__ W1t, short* __restrict__ W2t, short* __restrict__ W3t,
    short* __restrict__ Wf1t, short* __restrict__ Wf2t, short* __restrict__ Wf3t) {
  int tid = threadIdx.x, blk = blockIdx.x;
  if (blk >= EBLK) {
    int b = blk - EBLK;
    if (b < 5) {
      const float* W = (b == 0) ? W1 : (b == 1) ? W2 : (b == 2) ? W3 : (b == 3) ? Wf1 : Wf2;
      short* Wt = (b == 0) ? W1t : (b == 1) ? W2t : (b == 2) ? W3t : (b == 3) ? Wf1t : Wf2t;
#pragma unroll
      for (int i = 0; i < 16; ++i) {
        int idx = tid + 256 * i;       // = k*64 + n
        int k = idx >> 6, nn = idx & 63;
        Wt[nn * 64 + k] = (short)f2b(W[idx]);
      }
    } else {
#pragma unroll
      for (int i = 0; i < 4; ++i) {
        int idx = tid + 256 * i;       // = k*16 + n
        int k = idx >> 4, nn = idx & 15;
        Wf3t[nn * 64 + k] = (short)f2b(Wf3[idx]);
      }
    }
    return;
  }
  __shared__ int hist[256];
  __shared__ int lstart[256];
  __shared__ int gbase[256];
  __shared__ int cur[NBUK];
  __shared__ int wsum[4];
  __shared__ int2 sbuf[2048];
  int lane = tid & 63, wv = tid >> 6;
  hist[tid] = 0;
  __syncthreads();
  int base = blk * 2048;
  int dd[8], ss[8];
#pragma unroll
  for (int i = 0; i < 8; ++i) {
    int e = base + tid + 256 * i;
    if (e < NE) {
      dd[i] = dst[e]; ss[i] = src[e];
      atomicAdd(&hist[dd[i] >> 9], 1);
    } else dd[i] = -1;
  }
  __syncthreads();
  int v = hist[tid];
  int s = v;
#pragma unroll
  for (int off = 1; off < 64; off <<= 1) {
    int t = __shfl_up(s, off);
    if (lane >= off) s += t;
  }
  if (lane == 63) wsum[wv] = s;
  __syncthreads();
  int wpre = 0;
#pragma unroll
  for (int i = 0; i < 4; ++i) wpre += (i < wv) ? wsum[i] : 0;
  int excl = s + wpre - v;
  lstart[tid] = excl;
  if (tid < NBUK) {
    cur[tid] = 0;
    gbase[tid] = (v > 0) ? atomicAdd(&gcur[tid], v) : 0;
  }
  __syncthreads();
#pragma unroll
  for (int i = 0; i < 8; ++i) {
    if (dd[i] >= 0) {
      int b = dd[i] >> 9;
      int p = atomicAdd(&cur[b], 1);
      sbuf[lstart[b] + p] = make_int2((ss[i] << 9) | (dd[i] & 511), b);
    }
  }
  __syncthreads();
  int m = NE - base; if (m > 2048) m = 2048;
#pragma unroll
  for (int i = 0; i < 8; ++i) {
    int j = tid + 256 * i;
    if (j < m) {
      int2 e = sbuf[j];
      int b = e.y;
      int gpos = b * BSTRIDE + gbase[b] + (j - lstart[b]);
      ebuf[gpos] = e.x;
    }
  }
}

static __global__ __launch_bounds__(256) void k_bucket(const int* __restrict__ ebuf, const int* __restrict__ gcur,
                                                       int4* __restrict__ rc4, float* __restrict__ dis,
                                                       int* __restrict__ col_idx) {
  __shared__ int cnt[512];
  __shared__ int lrs[512];
  __shared__ int wsum[4];
  int b = blockIdx.x, tid = threadIdx.x;
  int lane = tid & 63, wv = tid >> 6;
  int base_n = b << 9;
  int ebeg = b * BSTRIDE;
  int m = gcur[b];
  cnt[tid] = 0; cnt[tid + 256] = 0;
  __syncthreads();
  for (int j = tid; j < m; j += 256) atomicAdd(&cnt[ebuf[ebeg + j] & 511], 1);
  __syncthreads();
  int v0 = cnt[2 * tid], v1 = cnt[2 * tid + 1];
  int sv = v0 + v1;
  int s = sv;
#pragma unroll
  for (int off = 1; off < 64; off <<= 1) {
    int t = __shfl_up(s, off);
    if (lane >= off) s += t;
  }
  if (lane == 63) wsum[wv] = s;
  __syncthreads();
  int wpre = 0;
#pragma unroll
  for (int i = 0; i < 4; ++i) wpre += (i < wv) ? wsum[i] : 0;
  int excl = s + wpre - sv;
  lrs[2 * tid] = excl;
  lrs[2 * tid + 1] = excl + v0;
  __syncthreads();
  for (int i = tid; i < 512; i += 256) {
    int n = base_n + i;
    if (n < NN) {
      int c = cnt[i];
      float d = 1.0f / sqrtf((float)c + 1.0f);
      rc4[n] = make_int4(ebeg + lrs[i], c, __float_as_int(d), 0);
      dis[n] = d;
    }
  }
  for (int i = tid; i < 512; i += 256) cnt[i] = lrs[i];
  __syncthreads();
  for (int j = tid; j < m; j += 256) {
    int e = ebuf[ebeg + j];
    int p = atomicAdd(&cnt[e & 511], 1);
    col_idx[ebeg + p] = e >> 9;
  }
}

__device__ __forceinline__ bf16x8 load_a_frag_f32(const float* __restrict__ p, bool valid) {
  float4 f0 = valid ? *(const float4*)p : make_float4(0.f, 0.f, 0.f, 0.f);
  float4 f1 = valid ? *(const float4*)(p + 4) : make_float4(0.f, 0.f, 0.f, 0.f);
  bf16x8 a;
  a[0] = (short)f2b(f0.x); a[1] = (short)f2b(f0.y); a[2] = (short)f2b(f0.z); a[3] = (short)f2b(f0.w);
  a[4] = (short)f2b(f1.x); a[5] = (short)f2b(f1.y); a[6] = (short)f2b(f1.z); a[7] = (short)f2b(f1.w);
  return a;
}

// shared MFMA body: writes ht (bf16, dis-scaled)
__device__ __forceinline__ void mm_body(bf16x8 a0, bf16x8 a1, const short* __restrict__ Wt,
                                        const float* __restrict__ dis, short* __restrict__ out,
                                        int row0, int rlane, int g, int n) {
  f32x4 acc[4];
#pragma unroll
  for (int t = 0; t < 4; ++t) acc[t] = (f32x4){0.f, 0.f, 0.f, 0.f};
#pragma unroll
  for (int t = 0; t < 4; ++t) {
    bf16x8 b0 = *(const bf16x8*)(Wt + (rlane + 16 * t) * 64 + g * 8);
    bf16x8 b1 = *(const bf16x8*)(Wt + (rlane + 16 * t) * 64 + g * 8 + 32);
    acc[t] = __builtin_amdgcn_mfma_f32_16x16x32_bf16(a0, b0, acc[t], 0, 0, 0);
    acc[t] = __builtin_amdgcn_mfma_f32_16x16x32_bf16(a1, b1, acc[t], 0, 0, 0);
  }
#pragma unroll
  for (int r = 0; r < 4; ++r) {
    int gr = row0 + g * 4 + r;
    if (gr < n) {
      float s = dis[gr];
#pragma unroll
      for (int t = 0; t < 4; ++t)
        out[(size_t)gr * 64 + rlane + 16 * t] = (short)f2b(acc[t][r] * s);
    }
  }
}

// layer-1: f32 input, ht1 = (x @ W1) * dis
static __global__ __launch_bounds__(256) void k_mm1(const float* __restrict__ in, const short* __restrict__ Wt,
                                                    const float* __restrict__ dis, short* __restrict__ out, int n) {
  int tid = threadIdx.x;
  int lane = tid & 63, w = tid >> 6;
  int row0 = blockIdx.x * 64 + w * 16;
  int rlane = lane & 15, g = lane >> 4;
  int arow = row0 + rlane;
  bool av = arow < n;
  const float* ap = in + (size_t)arow * 64 + g * 8;
  bf16x8 a0 = load_a_frag_f32(ap, av);
  bf16x8 a1 = load_a_frag_f32(ap + 32, av);
  mm_body(a0, a1, Wt, dis, out, row0, rlane, g, n);
}

// agg: ONE node per 8-lane group, 8 nodes/wave. Per 8-edge chunk: broadcast all
// 8 indices, issue ALL 8 row-loads (invalid -> row 0, cache-hot), wait once,
// accumulate guarded. Writes rows [wrow0, wrow0+8) of Hs.
__device__ __forceinline__ void agg8_to_lds(const short* __restrict__ ht, const int4* __restrict__ rc4,
                                            const int* __restrict__ col_idx,
                                            const float* __restrict__ bias, short (*Hs)[72],
                                            int nodebase, int wrow0, int lane, int n) {
  int g = lane >> 3, f = lane & 7;
  float4 b0v = *(const float4*)&bias[f * 8];
  float4 b1v = *(const float4*)&bias[f * 8 + 4];
  float bb[8] = {b0v.x, b0v.y, b0v.z, b0v.w, b1v.x, b1v.y, b1v.z, b1v.w};
  int node = nodebase + g;
  bool nv = node < n;
  int4 rcv = nv ? rc4[node] : make_int4(0, 0, 0, 0);
  int beg = rcv.x, cnt = rcv.y;
  float ds = nv ? __int_as_float(rcv.z) : 0.f;
  float acc[8] = {0.f, 0.f, 0.f, 0.f, 0.f, 0.f, 0.f, 0.f};
  if (nv) acc8(acc, *(const bf16x8*)(ht + (size_t)node * 64 + f * 8));   // self-loop
  for (int base = 0; base < cnt; base += 8) {
    int idx = (base + f < cnt) ? col_idx[beg + base + f] : 0;
    int s[8];
#pragma unroll
    for (int e = 0; e < 8; ++e) s[e] = __shfl(idx, g * 8 + e);
    bf16x8 r[8];
#pragma unroll
    for (int e = 0; e < 8; ++e) r[e] = *(const bf16x8*)(ht + (size_t)s[e] * 64 + f * 8);
    int mm = cnt - base; if (mm > 8) mm = 8;
#pragma unroll
    for (int e = 0; e < 8; ++e) { if (e < mm) acc8(acc, r[e]); }
  }
  bf16x8 o;
#pragma unroll
  for (int i = 0; i < 8; ++i)
    o[i] = (short)f2b(fmaxf(fmaf(ds, acc[i], bb[i]), 0.f));
  *(bf16x8*)&Hs[wrow0 + g][f * 8] = o;
}

// fused: agg -> matmul. 128 threads / 16 nodes / block (grid 6250 = 12500 waves).
// After one barrier the two waves split the 4 B-column tiles (2 each).
static __global__ __launch_bounds__(128) void k_aggmm(const short* __restrict__ ht, const int4* __restrict__ rc4,
                                                      const int* __restrict__ col_idx, const float* __restrict__ dis,
                                                      const float* __restrict__ bias, const short* __restrict__ Wt,
                                                      short* __restrict__ out, int n) {
  __shared__ __align__(16) short Hs[16][72];
  int tid = threadIdx.x;
  int lane = tid & 63, w = tid >> 6;
  int row0 = blockIdx.x * 16;
  agg8_to_lds(ht, rc4, col_idx, bias, Hs, row0 + w * 8, w * 8, lane, n);
  __syncthreads();
  int rlane = lane & 15, g = lane >> 4;
  bf16x8 a0 = *(const bf16x8*)&Hs[rlane][g * 8];
  bf16x8 a1 = *(const bf16x8*)&Hs[rlane][g * 8 + 32];
#pragma unroll
  for (int tt = 0; tt < 2; ++tt) {
    int t = 2 * w + tt;
    bf16x8 b0 = *(const bf16x8*)(Wt + (rlane + 16 * t) * 64 + g * 8);
    bf16x8 b1 = *(const bf16x8*)(Wt + (rlane + 16 * t) * 64 + g * 8 + 32);
    f32x4 acc = (f32x4){0.f, 0.f, 0.f, 0.f};
    acc = __builtin_amdgcn_mfma_f32_16x16x32_bf16(a0, b0, acc, 0, 0, 0);
    acc = __builtin_amdgcn_mfma_f32_16x16x32_bf16(a1, b1, acc, 0, 0, 0);
#pragma unroll
    for (int r = 0; r < 4; ++r) {
      int gr = row0 + g * 4 + r;
      if (gr < n) out[(size_t)gr * 64 + rlane + 16 * t] = (short)f2b(acc[r] * dis[gr]);
    }
  }
}

// fused: agg -> MLP head -> log_softmax. 128 threads / 16 nodes / block.
// L1/L2 split across the 2 waves (ping-pong LDS); L3+softmax on wave 0.
static __global__ __launch_bounds__(128) void k_aggdense(const short* __restrict__ ht, const int4* __restrict__ rc4,
    const int* __restrict__ col_idx, const float* __restrict__ bias,
    const short* __restrict__ W1t, const float* __restrict__ bf1,
    const short* __restrict__ W2t, const float* __restrict__ bf2,
    const short* __restrict__ W3t, const float* __restrict__ bf3,
    float* __restrict__ out, int n) {
  __shared__ __align__(16) short Hs[16][72];
  __shared__ __align__(16) short H2[16][72];
  int tid = threadIdx.x;
  int lane = tid & 63, w = tid >> 6;
  int row0 = blockIdx.x * 16;
  agg8_to_lds(ht, rc4, col_idx, bias, Hs, row0 + w * 8, w * 8, lane, n);
  __syncthreads();
  int rlane = lane & 15, g = lane >> 4;
  // L1: wave w computes col-tiles 2w, 2w+1 -> H2
  {
    bf16x8 a0 = *(const bf16x8*)&Hs[rlane][g * 8];
    bf16x8 a1 = *(const bf16x8*)&Hs[rlane][g * 8 + 32];
#pragma unroll
    for (int tt = 0; tt < 2; ++tt) {
      int t = 2 * w + tt;
      bf16x8 b0 = *(const bf16x8*)(W1t + (rlane + 16 * t) * 64 + g * 8);
      bf16x8 b1 = *(const bf16x8*)(W1t + (rlane + 16 * t) * 64 + g * 8 + 32);
      f32x4 acc = (f32x4){0.f, 0.f, 0.f, 0.f};
      acc = __builtin_amdgcn_mfma_f32_16x16x32_bf16(a0, b0, acc, 0, 0, 0);
      acc = __builtin_amdgcn_mfma_f32_16x16x32_bf16(a1, b1, acc, 0, 0, 0);
      float bb = bf1[16 * t + rlane];
#pragma unroll
      for (int r = 0; r < 4; ++r)
        H2[g * 4 + r][16 * t + rlane] = (short)f2b(fmaxf(acc[r] + bb, 0.f));
    }
  }
  __syncthreads();
  // L2: H2 -> Hs
  {
    bf16x8 c0 = *(const bf16x8*)&H2[rlane][g * 8];
    bf16x8 c1 = *(const bf16x8*)&H2[rlane][g * 8 + 32];
#pragma unroll
    for (int tt = 0; tt < 2; ++tt) {
      int t = 2 * w + tt;
      bf16x8 b0 = *(const bf16x8*)(W2t + (rlane + 16 * t) * 64 + g * 8);
      bf16x8 b1 = *(const bf16x8*)(W2t + (rlane + 16 * t) * 64 + g * 8 + 32);
      f32x4 acc = (f32x4){0.f, 0.f, 0.f, 0.f};
      acc = __builtin_amdgcn_mfma_f32_16x16x32_bf16(c0, b0, acc, 0, 0, 0);
      acc = __builtin_amdgcn_mfma_f32_16x16x32_bf16(c1, b1, acc, 0, 0, 0);
      float bb = bf2[16 * t + rlane];
#pragma unroll
      for (int r = 0; r < 4; ++r)
        Hs[g * 4 + r][16 * t + rlane] = (short)f2b(fmaxf(acc[r] + bb, 0.f));
    }
  }
  __syncthreads();
  // L3 + log_softmax: wave 0 only (16 output classes, one 16x16x64 job)
  if (w == 0) {
    bf16x8 d0 = *(const bf16x8*)&Hs[rlane][g * 8];
    bf16x8 d1 = *(const bf16x8*)&Hs[rlane][g * 8 + 32];
    bf16x8 e0 = *(const bf16x8*)(W3t + rlane * 64 + g * 8);
    bf16x8 e1 = *(const bf16x8*)(W3t + rlane * 64 + g * 8 + 32);
    f32x4 z = (f32x4){0.f, 0.f, 0.f, 0.f};
    z = __builtin_amdgcn_mfma_f32_16x16x32_bf16(d0, e0, z, 0, 0, 0);
    z = __builtin_amdgcn_mfma_f32_16x16x32_bf16(d1, e1, z, 0, 0, 0);
    float bsc = bf3[rlane];
#pragma unroll
    for (int r = 0; r < 4; ++r) {
      float zz = z[r] + bsc;
      float mx = zz;
      mx = fmaxf(mx, __shfl_xor(mx, 1));
      mx = fmaxf(mx, __shfl_xor(mx, 2));
      mx = fmaxf(mx, __shfl_xor(mx, 4));
      mx = fmaxf(mx, __shfl_xor(mx, 8));
      float ex = __expf(zz - mx);
      ex += __shfl_xor(ex, 1);
      ex += __shfl_xor(ex, 2);
      ex += __shfl_xor(ex, 4);
      ex += __shfl_xor(ex, 8);
      float lse = mx + __logf(ex);
      int gr = row0 + g * 4 + r;
      if (gr < n) out[(size_t)gr * 16 + rlane] = zz - lse;
    }
  }
}

extern "C" void kernel_launch(void* const* d_in, const int* in_sizes, int n_in,
                              void* d_out, int out_size, void* d_ws, size_t ws_size,
                              hipStream_t stream) {
  (void)in_sizes; (void)n_in; (void)out_size; (void)ws_size;
  const float* x   = (const float*)d_in[0];
  const int*   ei  = (const int*)d_in[1];
  const float* W1  = (const float*)d_in[2];
  const float* b1  = (const float*)d_in[3];
  const float* W2  = (const float*)d_in[4];
  const float* b2  = (const float*)d_in[5];
  const float* W3  = (const float*)d_in[6];
  const float* b3  = (const float*)d_in[7];
  const float* Wf1 = (const float*)d_in[8];
  const float* bf1 = (const float*)d_in[9];
  const float* Wf2 = (const float*)d_in[10];
  const float* bf2 = (const float*)d_in[11];
  const float* Wf3 = (const float*)d_in[12];
  const float* bf3 = (const float*)d_in[13];
  float* outp = (float*)d_out;
  const int* srcp = ei;
  const int* dstp = ei + NE;

  char* ws = (char*)d_ws;
  size_t off = 0;
  auto alloc = [&](size_t bytes) { void* p = ws + off; off = (off + bytes + 255) & ~(size_t)255; return p; };
  int4*  rc4    = (int4*)alloc((size_t)NN * 16);
  float* dis    = (float*)alloc((size_t)NN * 4);
  int*   gcur   = (int*)alloc(256 * 4);
  int*   colidx = (int*)alloc((size_t)NBUK * BSTRIDE * 4);
  short* W1t    = (short*)alloc(4096 * 2);
  short* W2t    = (short*)alloc(4096 * 2);
  short* W3t    = (short*)alloc(4096 * 2);
  short* Wf1t   = (short*)alloc(4096 * 2);
  short* Wf2t   = (short*)alloc(4096 * 2);
  short* Wf3t   = (short*)alloc(1024 * 2);
  short* bufA   = (short*)alloc((size_t)NN * 64 * 2);
  short* bufB   = (short*)alloc((size_t)NN * 64 * 2);
  int*   ebuf   = (int*)alloc((size_t)NBUK * BSTRIDE * 4);

  int gMM = (NN + 63) / 64;      // 1563 (256-thread blocks)
  int gAG = (NN + 15) / 16;      // 6250 (128-thread blocks, 12500 waves)

  hipMemsetAsync(gcur, 0, 256 * 4, stream);
  k_scwc<<<EBLK + 6, 256, 0, stream>>>(srcp, dstp, gcur, ebuf,
                                       W1, W2, W3, Wf1, Wf2, Wf3,
                                       W1t, W2t, W3t, Wf1t, Wf2t, Wf3t);
  k_bucket<<<NBUK, 256, 0, stream>>>(ebuf, gcur, rc4, dis, colidx);

  // ht1 = (x @ W1) * dis
  k_mm1<<<gMM, 256, 0, stream>>>(x, W1t, dis, bufB, NN);
  // h1 = relu(dis*(agg ht1) + b1); ht2 = (h1 @ W2) * dis
  k_aggmm<<<gAG, 128, 0, stream>>>(bufB, rc4, colidx, dis, b1, W2t, bufA, NN);
  // h2 = relu(dis*(agg ht2) + b2); ht3 = (h2 @ W3) * dis
  k_aggmm<<<gAG, 128, 0, stream>>>(bufA, rc4, colidx, dis, b2, W3t, bufB, NN);
  // h3 = relu(dis*(agg ht3) + b3); out = log_softmax(MLP(h3))
  k_aggdense<<<gAG, 128, 0, stream>>>(bufB, rc4, colidx, b3,
                                      Wf1t, bf1, Wf2t, bf2, Wf3t, bf3, outp, NN);
}